// Round 12
// baseline (46.857 us; speedup 1.0000x reference)
//
#include <hip/hip_runtime.h>
#include <hip/hip_fp16.h>

// Problem constants (match reference)
constexpr int Bc = 64;
constexpr int Nc = 32768;
constexpr int Kc = 128;
constexpr int Tc = 512;      // trajectory length
constexpr int TMAXc = 512;   // table time dim (== Tc)
constexpr int BK = Bc * Kc;  // 8192

typedef float f32x4 __attribute__((ext_vector_type(4)));
typedef float f32x2 __attribute__((ext_vector_type(2)));
typedef int   i32x2 __attribute__((ext_vector_type(2)));

// Workspace layout:
//   [0, 16777216)        table    (B,K,TMAX) half2 (4 B/slot)
//   [16777216, +4096)    partials 512 x float2
constexpr size_t TABLE_BYTES = (size_t)BK * TMAXc * 4;
constexpr int NBLK1 = BK / 2;   // 4096 blocks, 2 (b,k) pairs each
constexpr int NBLK2 = 512;      // 8 blocks per b (k-split), 2 blocks/CU

// ---------------- Phase 1: scatter traj xy into (B,K,TMAX) half2 table ------
// Two contiguous (b,k) pairs per block (exact 5-iter load balance), XCD
// affinity b % 8 == blockIdx % 8 so each b-slice is built in one XCD's L2.
// times is a permutation of 0..511 per (b,k): every slot is written.
// Measured ~14 us = its 101 MB roofline (R9 decomposition) — done.
__global__ __launch_bounds__(256) void build_table_k(
    const f32x4* __restrict__ traj4,   // (B,K,T,5) viewed as f32x4[BK*640]
    uint2* __restrict__ table2)        // (B,K,TMAX) half2 viewed as uint2[BK*256]
{
    __shared__ __align__(16) float    stage[2 * Tc * 5];  // 20480 B
    __shared__ __align__(8)  unsigned tbl[2 * TMAXc];     //  4096 B

    const int j   = blockIdx.x;
    const int xcd = j & 7;
    const int s   = j >> 3;                  // 0..511
    const int b   = ((s >> 6) << 3) | xcd;   // 0..63, b%8 == xcd
    const int k2  = s & 63;                  // pair-of-k index
    const int bk0 = (b << 7) | (k2 << 1);    // first of two contiguous (b,k)

    // coalesced nt load: 1280 f32x4 per block = exactly 5 per thread
    const f32x4* src = traj4 + (size_t)bk0 * 640;
    #pragma unroll
    for (int r = 0; r < 5; ++r) {
        int t = threadIdx.x + r * 256;
        ((f32x4*)stage)[t] = __builtin_nontemporal_load(&src[t]);
    }
    __syncthreads();

    // scatter 1024 records within LDS
    #pragma unroll
    for (int r = 0; r < 4; ++r) {
        int t = threadIdx.x + r * 256;         // 0..1023; pair = t>>9
        float x  = stage[t * 5 + 0];
        float y  = stage[t * 5 + 1];
        float tv = stage[t * 5 + 4];
        int tau = __float2int_rn(tv * 10.0f);      // matches jnp.round(...)
        if ((unsigned)tau < (unsigned)TMAXc) {     // mode='drop'
            __half2 p = __floats2half2_rn(x, y);
            unsigned raw;
            __builtin_memcpy(&raw, &p, 4);
            tbl[((t >> 9) << 9) + tau] = raw;
        }
    }
    __syncthreads();

    // coalesced cached store: 512 uint2 = exactly 2 per thread
    uint2* dst = table2 + (size_t)bk0 * 256;
    #pragma unroll
    for (int r = 0; r < 2; ++r) {
        int t = threadIdx.x + r * 256;
        dst[t] = ((const uint2*)tbl)[t];
    }
}

// ---------------- Phase 2: LDS-table gather + per-block partial reduction ---
// R6-R11 established: global gathers saturate at ~2.5 TB/s regardless of
// ILP/TLP. So take the random access off the VMEM path: block (b,q) holds
// k-slice [16q,16q+16) of b's table in 32 KB LDS and streams ALL of b's
// items, accepting those whose obj is in range (exactly one block per item).
// The random access becomes ds_read_b32. Streams use CACHED loads: 8 blocks
// of b share the same XCD (b%8 == j%8), so re-reads hit that XCD's L2.
__global__ __launch_bounds__(256) void gather_reduce_k(
    const f32x2*    __restrict__ state2,  // (B,N,4) viewed as f32x2 halves
    const i32x2*    __restrict__ tidx2,   // (B,N) as pairs
    const i32x2*    __restrict__ uid2,    // (B,N) as pairs
    const uint2*    __restrict__ table2,  // (B,K,TMAX) half2 as uint2
    float2*         __restrict__ partials)
{
    __shared__ unsigned tbl[16 * TMAXc];   // 32 KB k-slice
    __shared__ float2 lred[4];

    const int j   = blockIdx.x;
    const int xcd = j & 7;
    const int s   = j >> 3;                  // 0..63
    const int b   = ((s >> 3) << 3) | xcd;   // 0..63, b%8 == xcd
    const int q   = s & 7;                   // k-slice index, k in [16q,16q+16)

    // load this block's 32 KB table slice (L2/L3-resident from phase 1)
    const uint2* slice = table2 + ((size_t)b << 15) + (q << 12);  // uint2 units
    #pragma unroll
    for (int r = 0; r < 16; ++r) {
        int t = threadIdx.x + r * 256;
        ((uint2*)tbl)[t] = slice[t];
    }
    __syncthreads();

    // stream ALL of b's items: 16384 pairs, 8 chunks x 2048 pairs,
    // 8 pairs (16 items) per thread per chunk
    const int pbase = b << 14;               // first pair of b
    float sum = 0.0f, cnt = 0.0f;

    #pragma unroll 1
    for (int c = 0; c < 8; ++c) {
        i32x2 u[8], tv[8];
        #pragma unroll
        for (int r = 0; r < 8; ++r) {
            int p = pbase + (c << 11) + (r << 8) + threadIdx.x;
            u[r]  = uid2[p];                 // cached: 8 blocks share via L2
            tv[r] = tidx2[p];
        }
        unsigned g[16];
        #pragma unroll
        for (int r = 0; r < 8; ++r) {
            int o0 = min(max(u[r].x, 0), Kc - 1);
            int o1 = min(max(u[r].y, 0), Kc - 1);
            int t0 = min(max(tv[r].x, 0), TMAXc - 1);
            int t1 = min(max(tv[r].y, 0), TMAXc - 1);
            g[2*r]   = tbl[((o0 & 15) << 9) | t0];   // always-valid LDS addr
            g[2*r+1] = tbl[((o1 & 15) << 9) | t1];
        }
        f32x2 s0[8], s1[8];
        #pragma unroll
        for (int r = 0; r < 8; ++r) {
            int p = pbase + (c << 11) + (r << 8) + threadIdx.x;
            s0[r] = state2[4 * (size_t)p];       // item 2p   xy
            s1[r] = state2[4 * (size_t)p + 2];   // item 2p+1 xy
        }
        #pragma unroll
        for (int r = 0; r < 8; ++r) {
            int o0 = min(max(u[r].x, 0), Kc - 1);
            int o1 = min(max(u[r].y, 0), Kc - 1);
            __half2 p0, p1;
            __builtin_memcpy(&p0, &g[2*r], 4);
            __builtin_memcpy(&p1, &g[2*r+1], 4);
            if (u[r].x >= 0 && (o0 >> 4) == q) {
                sum += fabsf(s0[r].x - __low2float(p0)) +
                       fabsf(s0[r].y - __high2float(p0));
                cnt += 1.0f;
            }
            if (u[r].y >= 0 && (o1 >> 4) == q) {
                sum += fabsf(s1[r].x - __low2float(p1)) +
                       fabsf(s1[r].y - __high2float(p1));
                cnt += 1.0f;
            }
        }
    }

    // wave64 down-reduce, then cross-wave via LDS
    #pragma unroll
    for (int off = 32; off > 0; off >>= 1) {
        sum += __shfl_down(sum, off, 64);
        cnt += __shfl_down(cnt, off, 64);
    }
    const int lane = threadIdx.x & 63;
    const int w    = threadIdx.x >> 6;
    if (lane == 0) lred[w] = make_float2(sum, cnt);
    __syncthreads();
    if (threadIdx.x == 0) {
        float s2 = 0.0f, c2 = 0.0f;
        #pragma unroll
        for (int t = 0; t < 4; ++t) { s2 += lred[t].x; c2 += lred[t].y; }
        partials[j] = make_float2(s2, c2);
    }
}

// ---------------- Phase 3: deterministic final reduce -> loss ---------------
__global__ __launch_bounds__(512) void final_reduce_k(
    const float2* __restrict__ partials, float* __restrict__ out)
{
    float s, c;
    {
        float2 p = partials[threadIdx.x];   // exactly 512 partials
        s = p.x; c = p.y;
    }
    #pragma unroll
    for (int off = 32; off > 0; off >>= 1) {
        s += __shfl_down(s, off, 64);
        c += __shfl_down(c, off, 64);
    }
    __shared__ float2 lds[8];
    int lane = threadIdx.x & 63;
    int w    = threadIdx.x >> 6;
    if (lane == 0) lds[w] = make_float2(s, c);
    __syncthreads();
    if (threadIdx.x == 0) {
        float s2 = 0.0f, c2 = 0.0f;
        #pragma unroll
        for (int t = 0; t < 8; ++t) { s2 += lds[t].x; c2 += lds[t].y; }
        out[0] = s2 / c2;
    }
}

extern "C" void kernel_launch(void* const* d_in, const int* in_sizes, int n_in,
                              void* d_out, int out_size, void* d_ws, size_t ws_size,
                              hipStream_t stream) {
    const f32x2* state2 = (const f32x2*)d_in[0];   // (B,N,4) f32
    const i32x2* tidx2  = (const i32x2*)d_in[1];   // (B,N)   i32
    const i32x2* uid2   = (const i32x2*)d_in[2];   // (B,N)   i32
    const f32x4* traj4  = (const f32x4*)d_in[3];   // (B,K,T,5) f32
    float* out = (float*)d_out;

    unsigned* table    = (unsigned*)d_ws;
    float2*   partials = (float2*)((char*)d_ws + TABLE_BYTES);

    build_table_k  <<<NBLK1, 256, 0, stream>>>(traj4, (uint2*)table);
    gather_reduce_k<<<NBLK2, 256, 0, stream>>>(state2, tidx2, uid2,
                                               (const uint2*)table, partials);
    final_reduce_k <<<1, 512, 0, stream>>>(partials, out);
}